// Round 2
// baseline (1346.475 us; speedup 1.0000x reference)
//
#include <hip/hip_runtime.h>
#include <stdint.h>

using half8 = __attribute__((ext_vector_type(8))) _Float16;
using half4 = __attribute__((ext_vector_type(4))) _Float16;
using f32x4 = __attribute__((ext_vector_type(4))) float;

#define BM 128
#define BN 128
#define BK 32
// LDS per stage buffer: Ahi[128][32]f16 (8KB) + Alo + Bhi + Blo = 32KB; double-buffered = 64KB
#define LDS_BUF 32768
#define OFF_AHI 0
#define OFF_ALO 8192
#define OFF_BHI 16384
#define OFF_BLO 24576

// XOR-swizzle: row stride 64B (32 f16), 4x 16B slots per row; slot ^= (row>>1)&3
// -> 16 lanes reading 16 rows at one k-chunk hit 2 lanes/bank-slot (free, m136).
__device__ __forceinline__ int swz(int row, int kb) {
  return (row << 6) + ((((kb >> 4) ^ ((row >> 1) & 3)) << 4) | (kb & 15));
}

__global__ __launch_bounds__(256, 2)
void gemm_split_f16(const float* __restrict__ A, const float* __restrict__ B,
                    const float* __restrict__ bias, float* __restrict__ C,
                    int M, int N, int K) {
  __shared__ char lds[2 * LDS_BUF];
  const int tid  = threadIdx.x;
  const int m0 = blockIdx.y * BM;
  const int n0 = blockIdx.x * BN;
  const int wave = tid >> 6, lane = tid & 63;
  const int wm = wave >> 1, wn = wave & 1;   // 2x2 wave grid, each wave owns 64x64
  const int NK = K / BK;

  f32x4 acc_hi[4][4], acc_mid[4][4];
#pragma unroll
  for (int m = 0; m < 4; m++)
#pragma unroll
    for (int n = 0; n < 4; n++) { acc_hi[m][n] = (f32x4)0.0f; acc_mid[m][n] = (f32x4)0.0f; }

  float4 ra[4], rb[4];   // staged global data held across compute (latency hiding)

  auto LOAD = [&](int ks) {
#pragma unroll
    for (int it = 0; it < 4; ++it) {
      int q = tid + (it << 8);          // 0..1023
      int row = q >> 3, k4 = q & 7;     // 128 rows x 8 float4
      ra[it] = *(const float4*)(A + (size_t)(m0 + row) * K + ks * BK + (k4 << 2));
      rb[it] = *(const float4*)(B + (size_t)(n0 + row) * K + ks * BK + (k4 << 2));
    }
  };

  auto WRITE = [&](int db) {
    char* base = lds + db * LDS_BUF;
#pragma unroll
    for (int it = 0; it < 4; ++it) {
      int q = tid + (it << 8);
      int row = q >> 3, k4 = q & 7;
      int off = swz(row, k4 << 3);      // 8-byte granule
      float va[4] = {ra[it].x, ra[it].y, ra[it].z, ra[it].w};
      float vb[4] = {rb[it].x, rb[it].y, rb[it].z, rb[it].w};
      half4 ah, al, bh, bl;
#pragma unroll
      for (int j = 0; j < 4; ++j) {
        _Float16 h = (_Float16)va[j];
        ah[j] = h; al[j] = (_Float16)((va[j] - (float)h) * 2048.0f);
        _Float16 g = (_Float16)vb[j];
        bh[j] = g; bl[j] = (_Float16)((vb[j] - (float)g) * 2048.0f);
      }
      *(half4*)(base + OFF_AHI + off) = ah;
      *(half4*)(base + OFF_ALO + off) = al;
      *(half4*)(base + OFF_BHI + off) = bh;
      *(half4*)(base + OFF_BLO + off) = bl;
    }
  };

  auto COMPUTE = [&](int db) {
    char* base = lds + db * LDS_BUF;
    const int kb = (lane >> 4) << 4;    // byte offset of this lane-group's K-chunk
    const int rl = lane & 15;
    half8 ah[4], al[4], bh[4], bl[4];
#pragma unroll
    for (int m = 0; m < 4; m++) {
      int off = swz(wm * 64 + m * 16 + rl, kb);
      ah[m] = *(half8*)(base + OFF_AHI + off);
      al[m] = *(half8*)(base + OFF_ALO + off);
    }
#pragma unroll
    for (int n = 0; n < 4; n++) {
      int off = swz(wn * 64 + n * 16 + rl, kb);
      bh[n] = *(half8*)(base + OFF_BHI + off);
      bl[n] = *(half8*)(base + OFF_BLO + off);
    }
#pragma unroll
    for (int m = 0; m < 4; m++)
#pragma unroll
      for (int n = 0; n < 4; n++) {
        acc_hi[m][n]  = __builtin_amdgcn_mfma_f32_16x16x32_f16(ah[m], bh[n], acc_hi[m][n], 0, 0, 0);
        acc_mid[m][n] = __builtin_amdgcn_mfma_f32_16x16x32_f16(ah[m], bl[n], acc_mid[m][n], 0, 0, 0);
        acc_mid[m][n] = __builtin_amdgcn_mfma_f32_16x16x32_f16(al[m], bh[n], acc_mid[m][n], 0, 0, 0);
      }
  };

  LOAD(0);
  WRITE(0);
  __syncthreads();
  for (int ks = 0; ks < NK; ++ks) {
    if (ks + 1 < NK) LOAD(ks + 1);        // issue next-tile global loads early
    COMPUTE(ks & 1);
    if (ks + 1 < NK) WRITE((ks + 1) & 1); // write other buffer (prev barrier protects)
    __syncthreads();
  }

  // Epilogue: C = acc_hi + acc_mid/2048 + bias. D-frag: col=lane&15, row=(lane>>4)*4+i
  const int col_l = lane & 15, rgrp = lane >> 4;
#pragma unroll
  for (int n = 0; n < 4; n++) {
    int col = n0 + wn * 64 + n * 16 + col_l;
    float bv = bias[col];
#pragma unroll
    for (int m = 0; m < 4; m++) {
      int rowb = m0 + wm * 64 + m * 16 + rgrp * 4;
#pragma unroll
      for (int i = 0; i < 4; i++) {
        float c = acc_hi[m][n][i] + acc_mid[m][n][i] * (1.0f / 2048.0f) + bv;
        C[(size_t)(rowb + i) * N + col] = c;
      }
    }
  }
}

// One block per row of Z [*, H]. Steps:
//  1) load row (16 floats/thread)
//  2) flag |z| < TAU; recompute flagged z exactly in fp64 from A[row,:K]·W[col,:K]+bias
//     (true sign; my split-f16 GEMM error ~2e-6 worst-case << TAU)
//  3) compute first all-pos / first all-neg group on corrected values
//  4) write scaled/zeroed groups (+ corrected elements already written in step 2)
__global__ __launch_bounds__(256)
void sda_fix_kernel(float* __restrict__ Z, const float* __restrict__ A,
                    const float* __restrict__ W, const float* __restrict__ bias,
                    int H, int K) {
  __shared__ int sPos[4], sNeg[4];
  __shared__ int nFix;
  __shared__ int fixIdx[64];
  __shared__ double sRed[4];
  const int row = blockIdx.x;
  float* zr = Z + (size_t)row * H;
  const int t = threadIdx.x;
  const float TAU = 1e-4f;

  if (t == 0) nFix = 0;
  __syncthreads();

  float v[16];
#pragma unroll
  for (int j = 0; j < 4; ++j) {
    float4 q = ((const float4*)zr)[(t << 2) + j];
    v[j * 4 + 0] = q.x; v[j * 4 + 1] = q.y; v[j * 4 + 2] = q.z; v[j * 4 + 3] = q.w;
  }
#pragma unroll
  for (int e = 0; e < 16; ++e) {
    if (fabsf(v[e]) < TAU) {
      int slot = atomicAdd(&nFix, 1);
      if (slot < 64) fixIdx[slot] = (t << 4) + e;
    }
  }
  __syncthreads();
  const int nf = min(nFix, 64);
  for (int i = 0; i < nf; ++i) {
    const int col = fixIdx[i];
    double s = 0.0;
    const float* ar = A + (size_t)row * K;
    const float* wr = W + (size_t)col * K;
    for (int k = t; k < K; k += 256) s += (double)ar[k] * (double)wr[k];
#pragma unroll
    for (int off = 32; off; off >>= 1) s += __shfl_xor(s, off);
    if ((t & 63) == 0) sRed[t >> 6] = s;
    __syncthreads();
    if (t == 0) {
      double tot = sRed[0] + sRed[1] + sRed[2] + sRed[3] + (double)bias[col];
      zr[col] = (float)tot;                  // corrected value in place
    }
    __syncthreads();
    if ((col >> 4) == t) v[col & 15] = zr[col];   // owner refreshes its copy
    __syncthreads();
  }

  // first all-pos / all-neg group over corrected values
  int fp = 0x7fffffff, fn = 0x7fffffff;
#pragma unroll
  for (int j = 0; j < 4; ++j) {
    bool ap = (v[j*4+0] > 0.f) & (v[j*4+1] > 0.f) & (v[j*4+2] > 0.f) & (v[j*4+3] > 0.f);
    bool an = (v[j*4+0] < 0.f) & (v[j*4+1] < 0.f) & (v[j*4+2] < 0.f) & (v[j*4+3] < 0.f);
    int g = (t << 2) + j;
    if (ap && g < fp) fp = g;
    if (an && g < fn) fn = g;
  }
#pragma unroll
  for (int off = 32; off; off >>= 1) {
    fp = min(fp, __shfl_xor(fp, off));
    fn = min(fn, __shfl_xor(fn, off));
  }
  if ((t & 63) == 0) { sPos[t >> 6] = fp; sNeg[t >> 6] = fn; }
  __syncthreads();
  fp = min(min(sPos[0], sPos[1]), min(sPos[2], sPos[3]));
  fn = min(min(sNeg[0], sNeg[1]), min(sNeg[2], sNeg[3]));
  const int act   = (fp == 0x7fffffff) ? -1 : fp;
  const int inact = (fn == 0x7fffffff) ? -1 : fn;
#pragma unroll
  for (int j = 0; j < 4; ++j) {
    int g = (t << 2) + j;
    if (g == act) {
      float4 w = { v[j*4+0]*2.f, v[j*4+1]*2.f, v[j*4+2]*2.f, v[j*4+3]*2.f };
      ((float4*)zr)[(t << 2) + j] = w;
    } else if (g == inact) {
      float4 w = {0.f, 0.f, 0.f, 0.f};
      ((float4*)zr)[(t << 2) + j] = w;
    }
  }
}

extern "C" void kernel_launch(void* const* d_in, const int* in_sizes, int n_in,
                              void* d_out, int out_size, void* d_ws, size_t ws_size,
                              hipStream_t stream) {
  const float* x  = (const float*)d_in[0];
  const float* W1 = (const float*)d_in[1];
  const float* b1 = (const float*)d_in[2];
  const float* W2 = (const float*)d_in[3];
  const float* b2 = (const float*)d_in[4];
  const float* W3 = (const float*)d_in[5];
  const float* b3 = (const float*)d_in[6];
  float* out = (float*)d_out;

  const int M = 8192, H = 4096, DIN = 1024, DOUT = 1024;
  float* Z1 = (float*)d_ws;                       // [8192,4096] f32
  float* Z2 = Z1 + (size_t)M * H;                 // [8192,4096] f32

  dim3 blk(256);
  // L1: Z1 = x @ W1^T + b1   (M=8192, N=4096, K=1024)
  gemm_split_f16<<<dim3(H / BN, M / BM), blk, 0, stream>>>(x, W1, b1, Z1, M, H, DIN);
  sda_fix_kernel<<<M, 256, 0, stream>>>(Z1, x, W1, b1, H, DIN);
  // L2: Z2 = Z1 @ W2^T + b2  (K=4096)
  gemm_split_f16<<<dim3(H / BN, M / BM), blk, 0, stream>>>(Z1, W2, b2, Z2, M, H, H);
  sda_fix_kernel<<<M, 256, 0, stream>>>(Z2, Z1, W2, b2, H, H);
  // L3: out = Z2 @ W3^T + b3 (N=1024)
  gemm_split_f16<<<dim3(DOUT / BN, M / BM), blk, 0, stream>>>(Z2, W3, b3, out, M, DOUT, H);
}

// Round 4
// 1192.399 us; speedup vs baseline: 1.1292x; 1.1292x over previous
//
#include <hip/hip_runtime.h>
#include <stdint.h>

using half8 = __attribute__((ext_vector_type(8))) _Float16;
using half4 = __attribute__((ext_vector_type(4))) _Float16;
using f32x4 = __attribute__((ext_vector_type(4))) float;

#define BM 128
#define BN 128
#define BK 32

// Bank-conflict-free layout: granule (row, k8) at byte row*64 + (k8 ^ ((row>>1)&3))*16.
// Read side uses swz(); GLD staging realizes it via pre-swizzled global source
// addresses (LDS dest must be linear: wave-uniform base + lane*16).
__device__ __forceinline__ int swz(int row, int kb) {
  return (row << 6) + ((((kb >> 4) ^ ((row >> 1) & 3)) << 4) | (kb & 15));
}

#define GLD(src, dst)                                                          \
  __builtin_amdgcn_global_load_lds(                                            \
      (const __attribute__((address_space(1))) void*)(src),                    \
      (__attribute__((address_space(3))) void*)(dst), 16, 0, 0)

// ---------------- L1: A,B f32 inputs, in-register split (round-2 proven) ----
// Epilogue emits hi/lo f16 split only (no f32 C).
#define LDS_BUF 32768
#define OFF_AHI 0
#define OFF_ALO 8192
#define OFF_BHI 16384
#define OFF_BLO 24576

__global__ __launch_bounds__(256, 2)
void gemm_l1(const float* __restrict__ A, const float* __restrict__ B,
             const float* __restrict__ bias,
             _Float16* __restrict__ Chi, _Float16* __restrict__ Clo,
             int M, int N, int K) {
  __shared__ char lds[2 * LDS_BUF];
  const int tid = threadIdx.x;
  const int m0 = blockIdx.y * BM;
  const int n0 = blockIdx.x * BN;
  const int wave = tid >> 6, lane = tid & 63;
  const int wm = wave >> 1, wn = wave & 1;
  const int NK = K / BK;

  f32x4 acc_hi[4][4], acc_mid[4][4];
#pragma unroll
  for (int m = 0; m < 4; m++)
#pragma unroll
    for (int n = 0; n < 4; n++) { acc_hi[m][n] = (f32x4)0.0f; acc_mid[m][n] = (f32x4)0.0f; }

  float4 ra[4], rb[4];

  auto LOAD = [&](int ks) {
#pragma unroll
    for (int it = 0; it < 4; ++it) {
      int q = tid + (it << 8);
      int row = q >> 3, k4 = q & 7;
      ra[it] = *(const float4*)(A + (size_t)(m0 + row) * K + ks * BK + (k4 << 2));
      rb[it] = *(const float4*)(B + (size_t)(n0 + row) * K + ks * BK + (k4 << 2));
    }
  };

  auto WRITE = [&](int db) {
    char* base = lds + db * LDS_BUF;
#pragma unroll
    for (int it = 0; it < 4; ++it) {
      int q = tid + (it << 8);
      int row = q >> 3, k4 = q & 7;
      int off = swz(row, k4 << 3);
      float va[4] = {ra[it].x, ra[it].y, ra[it].z, ra[it].w};
      float vb[4] = {rb[it].x, rb[it].y, rb[it].z, rb[it].w};
      half4 ah, al, bh, bl;
#pragma unroll
      for (int j = 0; j < 4; ++j) {
        _Float16 h = (_Float16)va[j];
        ah[j] = h; al[j] = (_Float16)((va[j] - (float)h) * 2048.0f);
        _Float16 g = (_Float16)vb[j];
        bh[j] = g; bl[j] = (_Float16)((vb[j] - (float)g) * 2048.0f);
      }
      *(half4*)(base + OFF_AHI + off) = ah;
      *(half4*)(base + OFF_ALO + off) = al;
      *(half4*)(base + OFF_BHI + off) = bh;
      *(half4*)(base + OFF_BLO + off) = bl;
    }
  };

  auto COMPUTE = [&](int db) {
    char* base = lds + db * LDS_BUF;
    const int kb = (lane >> 4) << 4;
    const int rl = lane & 15;
    half8 ah[4], al[4], bh[4], bl[4];
#pragma unroll
    for (int m = 0; m < 4; m++) {
      int off = swz(wm * 64 + m * 16 + rl, kb);
      ah[m] = *(half8*)(base + OFF_AHI + off);
      al[m] = *(half8*)(base + OFF_ALO + off);
    }
#pragma unroll
    for (int n = 0; n < 4; n++) {
      int off = swz(wn * 64 + n * 16 + rl, kb);
      bh[n] = *(half8*)(base + OFF_BHI + off);
      bl[n] = *(half8*)(base + OFF_BLO + off);
    }
#pragma unroll
    for (int m = 0; m < 4; m++)
#pragma unroll
      for (int n = 0; n < 4; n++) {
        acc_hi[m][n]  = __builtin_amdgcn_mfma_f32_16x16x32_f16(ah[m], bh[n], acc_hi[m][n], 0, 0, 0);
        acc_mid[m][n] = __builtin_amdgcn_mfma_f32_16x16x32_f16(ah[m], bl[n], acc_mid[m][n], 0, 0, 0);
        acc_mid[m][n] = __builtin_amdgcn_mfma_f32_16x16x32_f16(al[m], bh[n], acc_mid[m][n], 0, 0, 0);
      }
  };

  LOAD(0); WRITE(0);
  __syncthreads();
  for (int ks = 0; ks < NK; ++ks) {
    if (ks + 1 < NK) LOAD(ks + 1);
    COMPUTE(ks & 1);
    if (ks + 1 < NK) WRITE((ks + 1) & 1);
    __syncthreads();
  }

  const int col_l = lane & 15, rgrp = lane >> 4;
#pragma unroll
  for (int n = 0; n < 4; n++) {
    int col = n0 + wn * 64 + n * 16 + col_l;
    float bv = bias[col];
#pragma unroll
    for (int m = 0; m < 4; m++) {
      int rowb = m0 + wm * 64 + m * 16 + rgrp * 4;
#pragma unroll
      for (int i = 0; i < 4; i++) {
        float c = acc_hi[m][n][i] + acc_mid[m][n][i] * (1.0f / 2048.0f) + bv;
        size_t idx = (size_t)(rowb + i) * N + col;
        _Float16 hh = (_Float16)c;
        Chi[idx] = hh;
        Clo[idx] = (_Float16)((c - (float)hh) * 2048.0f);
      }
    }
  }
}

// ---------------- L2: all operands presplit f16, staged via global_load_lds --
// Epilogue emits f16 hi only.
__global__ __launch_bounds__(256, 2)
void gemm_l2(const _Float16* __restrict__ Ahi, const _Float16* __restrict__ Alo,
             const _Float16* __restrict__ Bhi, const _Float16* __restrict__ Blo,
             const float* __restrict__ bias, _Float16* __restrict__ Chi,
             int M, int N, int K) {
  __shared__ char lds[2 * LDS_BUF];
  const int tid = threadIdx.x;
  const int m0 = blockIdx.y * BM;
  const int n0 = blockIdx.x * BN;
  const int wave = tid >> 6, lane = tid & 63;
  const int wm = wave >> 1, wn = wave & 1;
  const int NK = K / BK;

  f32x4 acc_hi[4][4], acc_mid[4][4];
#pragma unroll
  for (int m = 0; m < 4; m++)
#pragma unroll
    for (int n = 0; n < 4; n++) { acc_hi[m][n] = (f32x4)0.0f; acc_mid[m][n] = (f32x4)0.0f; }

  // Pre-swizzled source: granule g=tid: row=g>>2, slot=g&3, src k8 = slot ^ ((row>>1)&3)
  // so linear LDS placement (base + lane*16) == swizzled layout.
  const int sr = tid >> 2;
  const int k8 = (tid & 3) ^ ((sr >> 1) & 3);
  const size_t aoff0 = (size_t)(m0 + sr) * K + k8 * 8;
  const size_t aoff1 = aoff0 + (size_t)64 * K;   // row+64: xor bits unchanged
  const size_t boff0 = (size_t)(n0 + sr) * K + k8 * 8;
  const size_t boff1 = boff0 + (size_t)64 * K;

  auto STAGE = [&](int db, int ks) {
    char* sb = lds + db * LDS_BUF + (wave << 10);   // wave-uniform LDS base
    const size_t ko = (size_t)ks * BK;
    GLD(Ahi + aoff0 + ko, sb + OFF_AHI);
    GLD(Ahi + aoff1 + ko, sb + OFF_AHI + 4096);
    GLD(Alo + aoff0 + ko, sb + OFF_ALO);
    GLD(Alo + aoff1 + ko, sb + OFF_ALO + 4096);
    GLD(Bhi + boff0 + ko, sb + OFF_BHI);
    GLD(Bhi + boff1 + ko, sb + OFF_BHI + 4096);
    GLD(Blo + boff0 + ko, sb + OFF_BLO);
    GLD(Blo + boff1 + ko, sb + OFF_BLO + 4096);
  };

  auto COMPUTE = [&](int db) {
    char* base = lds + db * LDS_BUF;
    const int kb = (lane >> 4) << 4;
    const int rl = lane & 15;
    half8 ah[4], al[4], bh[4], bl[4];
#pragma unroll
    for (int m = 0; m < 4; m++) {
      int off = swz(wm * 64 + m * 16 + rl, kb);
      ah[m] = *(half8*)(base + OFF_AHI + off);
      al[m] = *(half8*)(base + OFF_ALO + off);
    }
#pragma unroll
    for (int n = 0; n < 4; n++) {
      int off = swz(wn * 64 + n * 16 + rl, kb);
      bh[n] = *(half8*)(base + OFF_BHI + off);
      bl[n] = *(half8*)(base + OFF_BLO + off);
    }
#pragma unroll
    for (int m = 0; m < 4; m++)
#pragma unroll
      for (int n = 0; n < 4; n++) {
        acc_hi[m][n]  = __builtin_amdgcn_mfma_f32_16x16x32_f16(ah[m], bh[n], acc_hi[m][n], 0, 0, 0);
        acc_mid[m][n] = __builtin_amdgcn_mfma_f32_16x16x32_f16(ah[m], bl[n], acc_mid[m][n], 0, 0, 0);
        acc_mid[m][n] = __builtin_amdgcn_mfma_f32_16x16x32_f16(al[m], bh[n], acc_mid[m][n], 0, 0, 0);
      }
  };

  STAGE(0, 0);
  __syncthreads();
  for (int ks = 0; ks < NK; ++ks) {
    if (ks + 1 < NK) STAGE((ks + 1) & 1, ks + 1);
    COMPUTE(ks & 1);
    __syncthreads();
  }

  const int col_l = lane & 15, rgrp = lane >> 4;
#pragma unroll
  for (int n = 0; n < 4; n++) {
    int col = n0 + wn * 64 + n * 16 + col_l;
    float bv = bias[col];
#pragma unroll
    for (int m = 0; m < 4; m++) {
      int rowb = m0 + wm * 64 + m * 16 + rgrp * 4;
#pragma unroll
      for (int i = 0; i < 4; i++) {
        float c = acc_hi[m][n][i] + acc_mid[m][n][i] * (1.0f / 2048.0f) + bv;
        Chi[(size_t)(rowb + i) * N + col] = (_Float16)c;
      }
    }
  }
}

// ---------------- L3: A presplit-hi f16 via GLD, B f32 in-reg f16, hi-only ---
#define L3_STAGE 16384

__global__ __launch_bounds__(256, 2)
void gemm_l3(const _Float16* __restrict__ Ahi, const float* __restrict__ B,
             const float* __restrict__ bias, float* __restrict__ C,
             int M, int N, int K) {
  __shared__ char lds[2 * L3_STAGE];
  const int tid = threadIdx.x;
  const int m0 = blockIdx.y * BM;
  const int n0 = blockIdx.x * BN;
  const int wave = tid >> 6, lane = tid & 63;
  const int wm = wave >> 1, wn = wave & 1;
  const int NK = K / BK;

  f32x4 acc[4][4];
#pragma unroll
  for (int m = 0; m < 4; m++)
#pragma unroll
    for (int n = 0; n < 4; n++) acc[m][n] = (f32x4)0.0f;

  const int sr = tid >> 2;
  const int k8 = (tid & 3) ^ ((sr >> 1) & 3);
  const size_t aoff0 = (size_t)(m0 + sr) * K + k8 * 8;
  const size_t aoff1 = aoff0 + (size_t)64 * K;

  float4 rb[4];

  auto STAGEA = [&](int db, int ks) {
    char* sb = lds + db * L3_STAGE + (wave << 10);
    const size_t ko = (size_t)ks * BK;
    GLD(Ahi + aoff0 + ko, sb);
    GLD(Ahi + aoff1 + ko, sb + 4096);
  };
  auto LOADB = [&](int ks) {
#pragma unroll
    for (int it = 0; it < 4; ++it) {
      int q = tid + (it << 8);
      int row = q >> 3, k4 = q & 7;
      rb[it] = *(const float4*)(B + (size_t)(n0 + row) * K + ks * BK + (k4 << 2));
    }
  };
  auto WRITEB = [&](int db) {
    char* base = lds + db * L3_STAGE + 8192;
#pragma unroll
    for (int it = 0; it < 4; ++it) {
      int q = tid + (it << 8);
      int row = q >> 3, k4 = q & 7;
      int off = swz(row, k4 << 3);
      float vb[4] = {rb[it].x, rb[it].y, rb[it].z, rb[it].w};
      half4 bh;
#pragma unroll
      for (int j = 0; j < 4; ++j) bh[j] = (_Float16)vb[j];
      *(half4*)(base + off) = bh;
    }
  };

  auto COMPUTE = [&](int db) {
    char* base = lds + db * L3_STAGE;
    const int kb = (lane >> 4) << 4;
    const int rl = lane & 15;
    half8 ah[4], bh[4];
#pragma unroll
    for (int m = 0; m < 4; m++)
      ah[m] = *(half8*)(base + swz(wm * 64 + m * 16 + rl, kb));
#pragma unroll
    for (int n = 0; n < 4; n++)
      bh[n] = *(half8*)(base + 8192 + swz(wn * 64 + n * 16 + rl, kb));
#pragma unroll
    for (int m = 0; m < 4; m++)
#pragma unroll
      for (int n = 0; n < 4; n++)
        acc[m][n] = __builtin_amdgcn_mfma_f32_16x16x32_f16(ah[m], bh[n], acc[m][n], 0, 0, 0);
  };

  LOADB(0); STAGEA(0, 0); WRITEB(0);
  __syncthreads();
  for (int ks = 0; ks < NK; ++ks) {
    if (ks + 1 < NK) { LOADB(ks + 1); STAGEA((ks + 1) & 1, ks + 1); }
    COMPUTE(ks & 1);
    if (ks + 1 < NK) WRITEB((ks + 1) & 1);
    __syncthreads();
  }

  const int col_l = lane & 15, rgrp = lane >> 4;
#pragma unroll
  for (int n = 0; n < 4; n++) {
    int col = n0 + wn * 64 + n * 16 + col_l;
    float bv = bias[col];
#pragma unroll
    for (int m = 0; m < 4; m++) {
      int rowb = m0 + wm * 64 + m * 16 + rgrp * 4;
#pragma unroll
      for (int i = 0; i < 4; i++)
        C[(size_t)(rowb + i) * N + col] = acc[m][n][i] + bv;
    }
  }
}

// Split f32 -> (hi f16, lo f16 scaled by 2048). Grid-stride, float4 vectorized.
__global__ __launch_bounds__(256)
void split_kernel(const float* __restrict__ X, _Float16* __restrict__ Xhi,
                  _Float16* __restrict__ Xlo, size_t n4) {
  size_t i = (size_t)blockIdx.x * 256 + threadIdx.x;
  const size_t stride = (size_t)gridDim.x * 256;
  for (; i < n4; i += stride) {
    float4 q = ((const float4*)X)[i];
    float a[4] = {q.x, q.y, q.z, q.w};
    half4 h, l;
#pragma unroll
    for (int j = 0; j < 4; ++j) {
      _Float16 hh = (_Float16)a[j];
      h[j] = hh;
      l[j] = (_Float16)((a[j] - (float)hh) * 2048.0f);
    }
    ((half4*)Xhi)[i] = h;
    ((half4*)Xlo)[i] = l;
  }
}

// One block per row of Z (hi/lo f16 repr; Zlo may be null):
//  1) reconstruct row; flag |z| < TAU; recompute flagged cols in fp64 from the
//     f32 activation path (Af) or reconstructed hi/lo activations (true sign)
//  2) first all-pos / all-neg group on corrected values
//  3) write back changed elements (group scale/zero + borderline patches)
__global__ __launch_bounds__(256)
void sda_fix(_Float16* __restrict__ Zhi, _Float16* __restrict__ Zlo,
             const float* __restrict__ Af,
             const _Float16* __restrict__ Ahi, const _Float16* __restrict__ Alo,
             const float* __restrict__ W, const float* __restrict__ bias,
             int H, int K) {
  __shared__ int sPos[4], sNeg[4];
  __shared__ int nFix;
  __shared__ int fixIdx[64];
  __shared__ double sRed[4];
  __shared__ float sVal;
  const int row = blockIdx.x;
  _Float16* zh = Zhi + (size_t)row * H;
  _Float16* zl = Zlo ? Zlo + (size_t)row * H : nullptr;
  const int t = threadIdx.x;
  const float TAU = 1e-4f;

  if (t == 0) nFix = 0;
  __syncthreads();

  float v[16];
  {
    half8 a0 = ((const half8*)zh)[t * 2], a1 = ((const half8*)zh)[t * 2 + 1];
    if (zl) {
      half8 b0 = ((const half8*)zl)[t * 2], b1 = ((const half8*)zl)[t * 2 + 1];
#pragma unroll
      for (int e = 0; e < 8; ++e) {
        v[e]     = (float)a0[e] + (float)b0[e] * (1.0f / 2048.0f);
        v[8 + e] = (float)a1[e] + (float)b1[e] * (1.0f / 2048.0f);
      }
    } else {
#pragma unroll
      for (int e = 0; e < 8; ++e) { v[e] = (float)a0[e]; v[8 + e] = (float)a1[e]; }
    }
  }
#pragma unroll
  for (int e = 0; e < 16; ++e) {
    if (fabsf(v[e]) < TAU) {
      int slot = atomicAdd(&nFix, 1);
      if (slot < 64) fixIdx[slot] = (t << 4) + e;
    }
  }
  __syncthreads();
  const int nf = min(nFix, 64);
  unsigned fixmask = 0;
  for (int i = 0; i < nf; ++i) {
    const int col = fixIdx[i];
    double s = 0.0;
    const float* wr = W + (size_t)col * K;
    if (Af) {
      const float* ar = Af + (size_t)row * K;
      for (int k = t; k < K; k += 256) s += (double)ar[k] * (double)wr[k];
    } else {
      const _Float16* ah = Ahi + (size_t)row * K;
      const _Float16* al = Alo + (size_t)row * K;
      for (int k = t; k < K; k += 256)
        s += ((double)(float)ah[k] + (double)(float)al[k] * (1.0 / 2048.0)) * (double)wr[k];
    }
#pragma unroll
    for (int off = 32; off; off >>= 1) s += __shfl_xor(s, off);
    if ((t & 63) == 0) sRed[t >> 6] = s;
    __syncthreads();
    if (t == 0)
      sVal = (float)(sRed[0] + sRed[1] + sRed[2] + sRed[3] + (double)bias[col]);
    __syncthreads();
    if ((col >> 4) == t) { v[col & 15] = sVal; fixmask |= 1u << (col & 15); }
  }
  __syncthreads();

  int fp = 0x7fffffff, fn = 0x7fffffff;
#pragma unroll
  for (int j = 0; j < 4; ++j) {
    bool ap = (v[j*4+0] > 0.f) & (v[j*4+1] > 0.f) & (v[j*4+2] > 0.f) & (v[j*4+3] > 0.f);
    bool an = (v[j*4+0] < 0.f) & (v[j*4+1] < 0.f) & (v[j*4+2] < 0.f) & (v[j*4+3] < 0.f);
    int g = (t << 2) + j;
    if (ap && g < fp) fp = g;
    if (an && g < fn) fn = g;
  }
#pragma unroll
  for (int off = 32; off; off >>= 1) {
    fp = min(fp, __shfl_xor(fp, off));
    fn = min(fn, __shfl_xor(fn, off));
  }
  if ((t & 63) == 0) { sPos[t >> 6] = fp; sNeg[t >> 6] = fn; }
  __syncthreads();
  fp = min(min(sPos[0], sPos[1]), min(sPos[2], sPos[3]));
  fn = min(min(sNeg[0], sNeg[1]), min(sNeg[2], sNeg[3]));
  const int act   = (fp == 0x7fffffff) ? -1 : fp;
  const int inact = (fn == 0x7fffffff) ? -1 : fn;

  unsigned chg = fixmask;
#pragma unroll
  for (int j = 0; j < 4; ++j) {
    int g = (t << 2) + j;
    if (g == act) {
      v[j*4+0] *= 2.f; v[j*4+1] *= 2.f; v[j*4+2] *= 2.f; v[j*4+3] *= 2.f;
      chg |= 0xFu << (j * 4);
    } else if (g == inact) {
      v[j*4+0] = v[j*4+1] = v[j*4+2] = v[j*4+3] = 0.f;
      chg |= 0xFu << (j * 4);
    }
  }
  while (chg) {
    int e = __ffs(chg) - 1; chg &= chg - 1;
    float val = v[e];
    _Float16 hh = (_Float16)val;
    zh[(t << 4) + e] = hh;
    if (zl) zl[(t << 4) + e] = (_Float16)((val - (float)hh) * 2048.0f);
  }
}

extern "C" void kernel_launch(void* const* d_in, const int* in_sizes, int n_in,
                              void* d_out, int out_size, void* d_ws, size_t ws_size,
                              hipStream_t stream) {
  const float* x  = (const float*)d_in[0];
  const float* W1 = (const float*)d_in[1];
  const float* b1 = (const float*)d_in[2];
  const float* W2 = (const float*)d_in[3];
  const float* b2 = (const float*)d_in[4];
  const float* W3 = (const float*)d_in[5];
  const float* b3 = (const float*)d_in[6];
  float* out = (float*)d_out;

  const int M = 8192, H = 4096, DIN = 1024, DOUT = 1024;

  // Scratch layout: exactly 256 MiB (the footprint round 2 proved available).
  char* w = (char*)d_ws;
  _Float16* Z1hi = (_Float16*)w;  w += (size_t)M * H * 2;   //  64 MiB
  _Float16* Z1lo = (_Float16*)w;  w += (size_t)M * H * 2;   // 128 MiB
  _Float16* Z2hi = (_Float16*)w;  w += (size_t)M * H * 2;   // 192 MiB
  _Float16* W2hi = (_Float16*)w;  w += (size_t)H * H * 2;   // 224 MiB
  _Float16* W2lo = (_Float16*)w;  /* end = 256 MiB */

  // Presplit W2 (the operand reused by all 2048 L2 blocks).
  split_kernel<<<2048, 256, 0, stream>>>(W2, W2hi, W2lo, (size_t)H * H / 4);

  dim3 blk(256);
  // L1: Z1 = x @ W1^T + b1   (K=1024) — in-reg split, emits hi/lo
  gemm_l1<<<dim3(H / BN, M / BM), blk, 0, stream>>>(x, W1, b1, Z1hi, Z1lo, M, H, DIN);
  sda_fix<<<M, 256, 0, stream>>>(Z1hi, Z1lo, x, (const _Float16*)nullptr,
                                 (const _Float16*)nullptr, W1, b1, H, DIN);
  // L2: Z2 = Z1 @ W2^T + b2  (K=4096) — all presplit, GLD staging, emits hi
  gemm_l2<<<dim3(H / BN, M / BM), blk, 0, stream>>>(Z1hi, Z1lo, W2hi, W2lo, b2,
                                                    Z2hi, M, H, H);
  sda_fix<<<M, 256, 0, stream>>>(Z2hi, (_Float16*)nullptr, (const float*)nullptr,
                                 Z1hi, Z1lo, W2, b2, H, H);
  // L3: out = Z2 @ W3^T + b3 (N=1024) — hi-only f16
  gemm_l3<<<dim3(DOUT / BN, M / BM), blk, 0, stream>>>(Z2hi, W3, b3, out, M, DOUT, H);
}

// Round 5
// 1117.876 us; speedup vs baseline: 1.2045x; 1.0667x over previous
//
#include <hip/hip_runtime.h>
#include <stdint.h>

using half8 = __attribute__((ext_vector_type(8))) _Float16;
using half4 = __attribute__((ext_vector_type(4))) _Float16;
using f32x4 = __attribute__((ext_vector_type(4))) float;

#define BM 256
#define BN 128
#define BK 32

// Bank-conflict-free layout: granule (row, k8) at byte row*64 + (k8 ^ ((row>>1)&3))*16.
// Read side uses swz(); GLD staging realizes it via pre-swizzled global source
// addresses (LDS dest must be linear: wave-uniform base + lane*16).
__device__ __forceinline__ int swz(int row, int kb) {
  return (row << 6) + ((((kb >> 4) ^ ((row >> 1) & 3)) << 4) | (kb & 15));
}

#define GLD(src, dst)                                                          \
  __builtin_amdgcn_global_load_lds(                                            \
      (const __attribute__((address_space(1))) void*)(src),                    \
      (__attribute__((address_space(3))) void*)(dst), 16, 0, 0)

// Unified tri-buffer counted-vmcnt GEMM. C = A*B^T (+bias), split-f16 precision.
// MODE 0: hi/lo inputs -> Chi+Clo.  MODE 1: hi/lo inputs -> Chi only.
// MODE 2: hi-only inputs -> f32 C.
// Schedule: 3 LDS stages, depth-2 GLD prefetch, per-step {vmcnt(counted);
// s_barrier; issue GLDs for ks+2; ds_read; setprio(1) MFMA setprio(0)}.
// No wave ever ds_writes (all LDS writes via GLD) -> single barrier per step
// plus per-wave counted vmcnt covers all hazards (buffers ks / ks+1 / ks+2
// are distinct mod 3; a colliding write would require a wave 3 steps ahead,
// impossible with one barrier per step).
template <int MODE>
__global__ __launch_bounds__(512, 2)
void gemm_tri(const _Float16* __restrict__ Ahi, const _Float16* __restrict__ Alo,
              const _Float16* __restrict__ Bhi, const _Float16* __restrict__ Blo,
              const float* __restrict__ bias,
              _Float16* __restrict__ Chi, _Float16* __restrict__ Clo,
              float* __restrict__ Cf, int M, int N, int K) {
  constexpr bool LO = (MODE < 2);
  constexpr int AHI = 0;
  constexpr int ALO = 16384;                 // only if LO
  constexpr int BHI = LO ? 32768 : 16384;
  constexpr int BLO = LO ? 40960 : 0;        // only if LO
  constexpr int STG = LO ? 49152 : 24576;    // bytes per stage
  __shared__ char lds[3 * STG];

  const int tid = threadIdx.x;
  const int m0 = blockIdx.y * BM;
  const int n0 = blockIdx.x * BN;
  const int wave = tid >> 6, lane = tid & 63;
  const int wm = wave >> 1, wn = wave & 1;   // 4x2 wave grid; each wave owns 64x64
  const int NK = K / BK;

  f32x4 acc_hi[4][4], acc_mid[4][4];
#pragma unroll
  for (int m = 0; m < 4; m++)
#pragma unroll
    for (int n = 0; n < 4; n++) { acc_hi[m][n] = (f32x4)0.0f; acc_mid[m][n] = (f32x4)0.0f; }

  // Pre-swizzled global source: granule tid: srow = tid>>2 (0..127), slot = tid&3,
  // source k8 = slot ^ ((srow>>1)&3) so linear LDS placement == swizzled layout.
  // A second issue covers rows 128..255 (row+128 leaves bits 1-2 unchanged).
  const int srow = tid >> 2;
  const int kx = (tid & 3) ^ ((srow >> 1) & 3);
  const size_t aoff0 = (size_t)(m0 + srow) * K + kx * 8;
  const size_t aoff1 = aoff0 + (size_t)128 * K;
  const size_t boff  = (size_t)(n0 + srow) * K + kx * 8;

  auto STAGE = [&](int buf, int ks) {
    char* sb = lds + buf * STG + (wave << 10);   // wave-uniform LDS base
    const size_t ko = (size_t)ks * BK;
    GLD(Ahi + aoff0 + ko, sb + AHI);
    GLD(Ahi + aoff1 + ko, sb + AHI + 8192);
    GLD(Bhi + boff + ko, sb + BHI);
    if constexpr (LO) {
      GLD(Alo + aoff0 + ko, sb + ALO);
      GLD(Alo + aoff1 + ko, sb + ALO + 8192);
      GLD(Blo + boff + ko, sb + BLO);
    }
  };

  auto COMPUTE = [&](int buf) {
    char* base = lds + buf * STG;
    const int kb = (lane >> 4) << 4;
    const int rl = lane & 15;
    half8 ah[4], al[4], bh[4], bl[4];
#pragma unroll
    for (int m = 0; m < 4; m++) {
      int off = swz(wm * 64 + m * 16 + rl, kb);
      ah[m] = *(half8*)(base + AHI + off);
      if constexpr (LO) al[m] = *(half8*)(base + ALO + off);
    }
#pragma unroll
    for (int n = 0; n < 4; n++) {
      int off = swz(wn * 64 + n * 16 + rl, kb);
      bh[n] = *(half8*)(base + BHI + off);
      if constexpr (LO) bl[n] = *(half8*)(base + BLO + off);
    }
    __builtin_amdgcn_s_setprio(1);
#pragma unroll
    for (int m = 0; m < 4; m++)
#pragma unroll
      for (int n = 0; n < 4; n++) {
        acc_hi[m][n] = __builtin_amdgcn_mfma_f32_16x16x32_f16(ah[m], bh[n], acc_hi[m][n], 0, 0, 0);
        if constexpr (LO) {
          acc_mid[m][n] = __builtin_amdgcn_mfma_f32_16x16x32_f16(ah[m], bl[n], acc_mid[m][n], 0, 0, 0);
          acc_mid[m][n] = __builtin_amdgcn_mfma_f32_16x16x32_f16(al[m], bh[n], acc_mid[m][n], 0, 0, 0);
        }
      }
    __builtin_amdgcn_s_setprio(0);
  };

  STAGE(0, 0);
  STAGE(1, 1);
  int cur = 0;
  for (int ks = 0; ks < NK; ++ks) {
    if (ks + 1 < NK) {
      if constexpr (LO) asm volatile("s_waitcnt vmcnt(6)" ::: "memory");
      else              asm volatile("s_waitcnt vmcnt(3)" ::: "memory");
    } else {
      asm volatile("s_waitcnt vmcnt(0)" ::: "memory");
    }
    __builtin_amdgcn_s_barrier();
    if (ks + 2 < NK) {
      int nbuf = cur + 2; if (nbuf >= 3) nbuf -= 3;
      STAGE(nbuf, ks + 2);
    }
    COMPUTE(cur);
    if (++cur == 3) cur = 0;
  }

  // Epilogue. D-frag: col=lane&15, row=(lane>>4)*4+i.
  const int col_l = lane & 15, rgrp = lane >> 4;
#pragma unroll
  for (int n = 0; n < 4; n++) {
    int col = n0 + wn * 64 + n * 16 + col_l;
    float bv = bias[col];
#pragma unroll
    for (int m = 0; m < 4; m++) {
      int rowb = m0 + wm * 64 + m * 16 + rgrp * 4;
#pragma unroll
      for (int i = 0; i < 4; i++) {
        size_t idx = (size_t)(rowb + i) * N + col;
        if constexpr (MODE == 2) {
          Cf[idx] = acc_hi[m][n][i] + bv;
        } else {
          float c = acc_hi[m][n][i] + acc_mid[m][n][i] * (1.0f / 2048.0f) + bv;
          _Float16 hh = (_Float16)c;
          Chi[idx] = hh;
          if constexpr (MODE == 0) Clo[idx] = (_Float16)((c - (float)hh) * 2048.0f);
        }
      }
    }
  }
}

// Split f32 -> (hi f16, lo f16 scaled by 2048). Xlo may be null (hi-only).
__global__ __launch_bounds__(256)
void split_kernel(const float* __restrict__ X, _Float16* __restrict__ Xhi,
                  _Float16* __restrict__ Xlo, size_t n4) {
  size_t i = (size_t)blockIdx.x * 256 + threadIdx.x;
  const size_t stride = (size_t)gridDim.x * 256;
  for (; i < n4; i += stride) {
    float4 q = ((const float4*)X)[i];
    float a[4] = {q.x, q.y, q.z, q.w};
    half4 h, l;
#pragma unroll
    for (int j = 0; j < 4; ++j) {
      _Float16 hh = (_Float16)a[j];
      h[j] = hh;
      l[j] = (_Float16)((a[j] - (float)hh) * 2048.0f);
    }
    ((half4*)Xhi)[i] = h;
    if (Xlo) ((half4*)Xlo)[i] = l;
  }
}

// One block per row of Z (hi/lo f16 repr; Zlo may be null):
//  1) reconstruct row; flag |z| < TAU; recompute flagged cols in fp64 from the
//     f32 activation path (Af) or reconstructed hi/lo activations (true sign)
//  2) first all-pos / all-neg group on corrected values
//  3) write back changed elements (group scale/zero + borderline patches)
__global__ __launch_bounds__(256)
void sda_fix(_Float16* __restrict__ Zhi, _Float16* __restrict__ Zlo,
             const float* __restrict__ Af,
             const _Float16* __restrict__ Ahi, const _Float16* __restrict__ Alo,
             const float* __restrict__ W, const float* __restrict__ bias,
             int H, int K) {
  __shared__ int sPos[4], sNeg[4];
  __shared__ int nFix;
  __shared__ int fixIdx[64];
  __shared__ double sRed[4];
  __shared__ float sVal;
  const int row = blockIdx.x;
  _Float16* zh = Zhi + (size_t)row * H;
  _Float16* zl = Zlo ? Zlo + (size_t)row * H : nullptr;
  const int t = threadIdx.x;
  const float TAU = 1e-4f;

  if (t == 0) nFix = 0;
  __syncthreads();

  float v[16];
  {
    half8 a0 = ((const half8*)zh)[t * 2], a1 = ((const half8*)zh)[t * 2 + 1];
    if (zl) {
      half8 b0 = ((const half8*)zl)[t * 2], b1 = ((const half8*)zl)[t * 2 + 1];
#pragma unroll
      for (int e = 0; e < 8; ++e) {
        v[e]     = (float)a0[e] + (float)b0[e] * (1.0f / 2048.0f);
        v[8 + e] = (float)a1[e] + (float)b1[e] * (1.0f / 2048.0f);
      }
    } else {
#pragma unroll
      for (int e = 0; e < 8; ++e) { v[e] = (float)a0[e]; v[8 + e] = (float)a1[e]; }
    }
  }
#pragma unroll
  for (int e = 0; e < 16; ++e) {
    if (fabsf(v[e]) < TAU) {
      int slot = atomicAdd(&nFix, 1);
      if (slot < 64) fixIdx[slot] = (t << 4) + e;
    }
  }
  __syncthreads();
  const int nf = min(nFix, 64);
  unsigned fixmask = 0;
  for (int i = 0; i < nf; ++i) {
    const int col = fixIdx[i];
    double s = 0.0;
    const float* wr = W + (size_t)col * K;
    if (Af) {
      const float* ar = Af + (size_t)row * K;
      for (int k = t; k < K; k += 256) s += (double)ar[k] * (double)wr[k];
    } else {
      const _Float16* ah = Ahi + (size_t)row * K;
      const _Float16* al = Alo + (size_t)row * K;
      for (int k = t; k < K; k += 256)
        s += ((double)(float)ah[k] + (double)(float)al[k] * (1.0 / 2048.0)) * (double)wr[k];
    }
#pragma unroll
    for (int off = 32; off; off >>= 1) s += __shfl_xor(s, off);
    if ((t & 63) == 0) sRed[t >> 6] = s;
    __syncthreads();
    if (t == 0)
      sVal = (float)(sRed[0] + sRed[1] + sRed[2] + sRed[3] + (double)bias[col]);
    __syncthreads();
    if ((col >> 4) == t) { v[col & 15] = sVal; fixmask |= 1u << (col & 15); }
  }
  __syncthreads();

  int fp = 0x7fffffff, fn = 0x7fffffff;
#pragma unroll
  for (int j = 0; j < 4; ++j) {
    bool ap = (v[j*4+0] > 0.f) & (v[j*4+1] > 0.f) & (v[j*4+2] > 0.f) & (v[j*4+3] > 0.f);
    bool an = (v[j*4+0] < 0.f) & (v[j*4+1] < 0.f) & (v[j*4+2] < 0.f) & (v[j*4+3] < 0.f);
    int g = (t << 2) + j;
    if (ap && g < fp) fp = g;
    if (an && g < fn) fn = g;
  }
#pragma unroll
  for (int off = 32; off; off >>= 1) {
    fp = min(fp, __shfl_xor(fp, off));
    fn = min(fn, __shfl_xor(fn, off));
  }
  if ((t & 63) == 0) { sPos[t >> 6] = fp; sNeg[t >> 6] = fn; }
  __syncthreads();
  fp = min(min(sPos[0], sPos[1]), min(sPos[2], sPos[3]));
  fn = min(min(sNeg[0], sNeg[1]), min(sNeg[2], sNeg[3]));
  const int act   = (fp == 0x7fffffff) ? -1 : fp;
  const int inact = (fn == 0x7fffffff) ? -1 : fn;

  unsigned chg = fixmask;
#pragma unroll
  for (int j = 0; j < 4; ++j) {
    int g = (t << 2) + j;
    if (g == act) {
      v[j*4+0] *= 2.f; v[j*4+1] *= 2.f; v[j*4+2] *= 2.f; v[j*4+3] *= 2.f;
      chg |= 0xFu << (j * 4);
    } else if (g == inact) {
      v[j*4+0] = v[j*4+1] = v[j*4+2] = v[j*4+3] = 0.f;
      chg |= 0xFu << (j * 4);
    }
  }
  while (chg) {
    int e = __ffs(chg) - 1; chg &= chg - 1;
    float val = v[e];
    _Float16 hh = (_Float16)val;
    zh[(t << 4) + e] = hh;
    if (zl) zl[(t << 4) + e] = (_Float16)((val - (float)hh) * 2048.0f);
  }
}

extern "C" void kernel_launch(void* const* d_in, const int* in_sizes, int n_in,
                              void* d_out, int out_size, void* d_ws, size_t ws_size,
                              hipStream_t stream) {
  const float* x  = (const float*)d_in[0];
  const float* W1 = (const float*)d_in[1];
  const float* b1 = (const float*)d_in[2];
  const float* W2 = (const float*)d_in[3];
  const float* b2 = (const float*)d_in[4];
  const float* W3 = (const float*)d_in[5];
  const float* b3 = (const float*)d_in[6];
  float* out = (float*)d_out;

  const int M = 8192, H = 4096, DIN = 1024, DOUT = 1024;

  // Scratch: 256 MiB total, with time-sliced aliasing.
  //   @0   Z1hi 64MB              (dead after sda_fix(L2); W3hi reuses @64)
  //   @64  Z1lo 64MB
  //   @128 Z2hi 64MB — before L2, aliased as xhi(16) xlo(16) W1hi(8) W1lo(8)
  //   @192 W2hi 32MB
  //   @224 W2lo 32MB
  char* w = (char*)d_ws;
  _Float16* Z1hi = (_Float16*)(w + 0);
  _Float16* Z1lo = (_Float16*)(w + ((size_t)64 << 20));
  _Float16* Z2hi = (_Float16*)(w + ((size_t)128 << 20));
  _Float16* W2hi = (_Float16*)(w + ((size_t)192 << 20));
  _Float16* W2lo = (_Float16*)(w + ((size_t)224 << 20));
  // aliases (dead before their region's long-term owner is written)
  _Float16* xhi  = (_Float16*)(w + ((size_t)128 << 20));
  _Float16* xlo  = (_Float16*)(w + ((size_t)144 << 20));
  _Float16* W1hi = (_Float16*)(w + ((size_t)160 << 20));
  _Float16* W1lo = (_Float16*)(w + ((size_t)168 << 20));
  _Float16* W3hi = (_Float16*)(w + ((size_t)64 << 20));   // after sda_fix(L2)

  auto split = [&](const float* src, _Float16* hi, _Float16* lo, size_t n) {
    size_t n4 = n >> 2;
    int grid = (int)((n4 + 255) / 256);
    if (grid > 2048) grid = 2048;
    split_kernel<<<grid, 256, 0, stream>>>(src, hi, lo, n4);
  };
  split(x,  xhi,  xlo,  (size_t)M * DIN);
  split(W1, W1hi, W1lo, (size_t)H * DIN);
  split(W2, W2hi, W2lo, (size_t)H * H);

  dim3 blk(512);
  // L1: Z1 = x @ W1^T + b1   (K=1024) — presplit in, hi/lo out
  gemm_tri<0><<<dim3(H / BN, M / BM), blk, 0, stream>>>(
      xhi, xlo, W1hi, W1lo, b1, Z1hi, Z1lo, (float*)nullptr, M, H, DIN);
  sda_fix<<<M, 256, 0, stream>>>(Z1hi, Z1lo, x, (const _Float16*)nullptr,
                                 (const _Float16*)nullptr, W1, b1, H, DIN);
  // L2: Z2 = Z1 @ W2^T + b2  (K=4096) — presplit in, hi out (overwrites x/W1 splits)
  gemm_tri<1><<<dim3(H / BN, M / BM), blk, 0, stream>>>(
      Z1hi, Z1lo, W2hi, W2lo, b2, Z2hi, (_Float16*)nullptr, (float*)nullptr, M, H, H);
  sda_fix<<<M, 256, 0, stream>>>(Z2hi, (_Float16*)nullptr, (const float*)nullptr,
                                 Z1hi, Z1lo, W2, b2, H, H);
  // L3: out = Z2 @ W3^T + b3 (N=1024) — hi-only (W3hi reuses dead Z1lo region)
  split(W3, W3hi, (_Float16*)nullptr, (size_t)DOUT * H);
  gemm_tri<2><<<dim3(DOUT / BN, M / BM), blk, 0, stream>>>(
      Z2hi, (const _Float16*)nullptr, W3hi, (const _Float16*)nullptr, b3,
      (_Float16*)nullptr, (_Float16*)nullptr, out, M, DOUT, H);
}